// Round 4
// baseline (1041.833 us; speedup 1.0000x reference)
//
#include <hip/hip_runtime.h>
#include <math.h>

#define TSEQ 512
#define FDIM 64
#define HDIM 128
#define NB   512

typedef __attribute__((ext_vector_type(8))) short short8;
typedef __attribute__((ext_vector_type(4))) float f32x4;

__device__ __forceinline__ float fast_sig(float x) {
    return __builtin_amdgcn_rcpf(1.0f + __expf(-x));
}
__device__ __forceinline__ float fast_tanh(float x) {
    return 1.0f - 2.0f * __builtin_amdgcn_rcpf(1.0f + __expf(2.0f * x));
}
__device__ __forceinline__ unsigned short bf16_rn(float v) {
    unsigned u = __float_as_uint(v);
    u += 0x7FFF + ((u >> 16) & 1);
    return (unsigned short)(u >> 16);
}
__device__ __forceinline__ void cvt_hilo(float v, unsigned short& hi, unsigned short& lo) {
    hi = bf16_rn(v);
    lo = bf16_rn(v - __uint_as_float((unsigned)hi << 16));
}
__device__ __forceinline__ unsigned cvt_pk(float a, float b) {
    unsigned r;
    asm("v_cvt_pk_bf16_f32 %0, %1, %2" : "=v"(r) : "v"(a), "v"(b));
    return r;
}
__device__ __forceinline__ f32x4 mfma16(short8 a, short8 b, f32x4 c) {
    return __builtin_amdgcn_mfma_f32_16x16x32_bf16(a, b, c, 0, 0, 0);
}

union U8 { unsigned u[4]; short8 s; };

// 8 f32 -> hi/lo bf16 short8 pair (RNE, hi + residual)
__device__ __forceinline__ void pack8(float4 a, float4 b, short8& hi, short8& lo) {
    U8 H, L;
    H.u[0] = cvt_pk(a.x, a.y); H.u[1] = cvt_pk(a.z, a.w);
    H.u[2] = cvt_pk(b.x, b.y); H.u[3] = cvt_pk(b.z, b.w);
    L.u[0] = cvt_pk(a.x - __uint_as_float(H.u[0] << 16),
                    a.y - __uint_as_float(H.u[0] & 0xFFFF0000u));
    L.u[1] = cvt_pk(a.z - __uint_as_float(H.u[1] << 16),
                    a.w - __uint_as_float(H.u[1] & 0xFFFF0000u));
    L.u[2] = cvt_pk(b.x - __uint_as_float(H.u[2] << 16),
                    b.y - __uint_as_float(H.u[2] & 0xFFFF0000u));
    L.u[3] = cvt_pk(b.z - __uint_as_float(H.u[3] << 16),
                    b.w - __uint_as_float(H.u[3] & 0xFFFF0000u));
    hi = H.s; lo = L.s;
}

// ---------------- pre-GEMM: gi[t][b][384] = x(t,b,:)·W_ih^T + biases --------
// No LDS, no barriers. 1024 blocks x 512 thr; wave w owns gate rows w*16 of
// each kind; B-frags loaded per-lane from global (tile is L1-hot per block).
__global__ __launch_bounds__(512)
void gi_gemm(const float* __restrict__ x,
             const float* __restrict__ W_ih,
             const float* __restrict__ b_ih,
             const float* __restrict__ b_hh,
             float* __restrict__ gi)
{
    const int tid  = threadIdx.x;
    const int w    = tid >> 6;
    const int lane = tid & 63;
    const int g4   = lane >> 4;
    const int bcol = lane & 15;
    const int b0   = blockIdx.x * 16;
    const int t0   = blockIdx.y * 16;

    short8 Wih_hi[3][2], Wih_lo[3][2];
    #pragma unroll
    for (int kd = 0; kd < 3; ++kd) {
        const int g = kd * 128 + w * 16 + bcol;
        #pragma unroll
        for (int kt = 0; kt < 2; ++kt) {
            const float* p = W_ih + g * FDIM + kt * 32 + g4 * 8;
            short8 hi8, lo8;
            #pragma unroll
            for (int e = 0; e < 8; ++e) {
                unsigned short h_, l_;
                cvt_hilo(p[e], h_, l_);
                hi8[e] = (short)h_; lo8[e] = (short)l_;
            }
            Wih_hi[kd][kt] = hi8; Wih_lo[kd][kt] = lo8;
        }
    }
    f32x4 biasR, biasZ, biasN;
    #pragma unroll
    for (int i = 0; i < 4; ++i) {
        const int gr = w * 16 + g4 * 4 + i;
        biasR[i] = b_ih[gr]       + b_hh[gr];         // r: fold both biases
        biasZ[i] = b_ih[128 + gr] + b_hh[128 + gr];   // z: fold both
        biasN[i] = b_ih[256 + gr];                    // n: input bias only
    }

    for (int tt = 0; tt < 16; ++tt) {
        const int t = t0 + tt;
        const float* xp = x + ((size_t)(b0 + bcol) * TSEQ + t) * FDIM;
        short8 xh[2], xl[2];
        #pragma unroll
        for (int kt = 0; kt < 2; ++kt) {
            float4 a = *(const float4*)(xp + kt * 32 + g4 * 8);
            float4 b = *(const float4*)(xp + kt * 32 + g4 * 8 + 4);
            pack8(a, b, xh[kt], xl[kt]);
        }
        f32x4 acc0 = biasR, acc1 = biasZ, acc2 = biasN;
        #pragma unroll
        for (int kt = 0; kt < 2; ++kt) {
            acc0 = mfma16(Wih_lo[0][kt], xh[kt], acc0);
            acc0 = mfma16(Wih_hi[0][kt], xl[kt], acc0);
            acc0 = mfma16(Wih_hi[0][kt], xh[kt], acc0);
            acc1 = mfma16(Wih_lo[1][kt], xh[kt], acc1);
            acc1 = mfma16(Wih_hi[1][kt], xl[kt], acc1);
            acc1 = mfma16(Wih_hi[1][kt], xh[kt], acc1);
            acc2 = mfma16(Wih_lo[2][kt], xh[kt], acc2);
            acc2 = mfma16(Wih_hi[2][kt], xl[kt], acc2);
            acc2 = mfma16(Wih_hi[2][kt], xh[kt], acc2);
        }
        float* gp = gi + ((size_t)t * NB + (b0 + bcol)) * 384 + w * 16 + g4 * 4;
        *(f32x4*)(gp)       = acc0;
        *(f32x4*)(gp + 128) = acc1;
        *(f32x4*)(gp + 256) = acc2;
    }
}

// ---------------- recurrence ------------------------------------------------
// 32 blocks x 16 batches, 8 waves. LDS holds ONLY h (dbuf) + psum (dbuf).
// Step structure: [reads: psum(cur), h(cur), gi/x global] -> barrier 1 ->
// [writes: h(nxt), psum(nxt)] -> barrier 2. Full read/write separation.
template<bool USE_GI>
__global__ __launch_bounds__(512)
void gru_rec(const float* __restrict__ x,
             const float* __restrict__ W_ih,
             const float* __restrict__ W_hh,
             const float* __restrict__ b_ih,
             const float* __restrict__ b_hh,
             const float* __restrict__ W_out,
             const float* __restrict__ b_out,
             const float* __restrict__ gi,
             float* __restrict__ out)
{
    const int tid  = threadIdx.x;
    const int w    = tid >> 6;
    const int lane = tid & 63;
    const int g4   = lane >> 4;
    const int bcol = lane & 15;
    const int b0   = blockIdx.x * 16;

    __shared__ __align__(16) short h_s[2][16][136];   // +8 pad
    __shared__ float psum_s[2][8][16];

    short8 Whh_hi[3][4], Whh_lo[3][4];
    #pragma unroll
    for (int kd = 0; kd < 3; ++kd) {
        const int g = kd * 128 + w * 16 + bcol;
        #pragma unroll
        for (int kt = 0; kt < 4; ++kt) {
            const float* p = W_hh + g * HDIM + kt * 32 + g4 * 8;
            short8 hi8, lo8;
            #pragma unroll
            for (int e = 0; e < 8; ++e) {
                unsigned short h_, l_;
                cvt_hilo(p[e], h_, l_);
                hi8[e] = (short)h_; lo8[e] = (short)l_;
            }
            Whh_hi[kd][kt] = hi8; Whh_lo[kd][kt] = lo8;
        }
    }
    short8 Wih_hi[3][2], Wih_lo[3][2];
    if constexpr (!USE_GI) {
        #pragma unroll
        for (int kd = 0; kd < 3; ++kd) {
            const int g = kd * 128 + w * 16 + bcol;
            #pragma unroll
            for (int kt = 0; kt < 2; ++kt) {
                const float* p = W_ih + g * FDIM + kt * 32 + g4 * 8;
                short8 hi8, lo8;
                #pragma unroll
                for (int e = 0; e < 8; ++e) {
                    unsigned short h_, l_;
                    cvt_hilo(p[e], h_, l_);
                    hi8[e] = (short)h_; lo8[e] = (short)l_;
                }
                Wih_hi[kd][kt] = hi8; Wih_lo[kd][kt] = lo8;
            }
        }
    }

    f32x4 biasR, biasZ, biasNI, biasNH;
    float wout[4], h_old[4];
    #pragma unroll
    for (int i = 0; i < 4; ++i) {
        const int gr = w * 16 + g4 * 4 + i;
        biasR[i]  = b_ih[gr]       + b_hh[gr];
        biasZ[i]  = b_ih[128 + gr] + b_hh[128 + gr];
        biasNI[i] = b_ih[256 + gr];
        biasNH[i] = b_hh[256 + gr];
        wout[i]   = W_out[gr];
        h_old[i]  = 0.0f;
    }
    const float bout = b_out[0];

    {   // zero h buffer 0 (all we read at t=0)
        unsigned* hp = (unsigned*)&h_s[0][0][0];
        for (int i = tid; i < 16 * 136 / 2; i += 512) hp[i] = 0u;
    }

    // prefetch gi(0)
    f32x4 giR, giZ, giN;
    if constexpr (USE_GI) {
        const float* gp = gi + ((size_t)0 * NB + (b0 + bcol)) * 384 + w * 16 + g4 * 4;
        giR = *(const f32x4*)(gp);
        giZ = *(const f32x4*)(gp + 128);
        giN = *(const f32x4*)(gp + 256);
    }
    __syncthreads();

    for (int t = 0; t < TSEQ; ++t) {
        const int cur = t & 1, nxt = cur ^ 1;

        // ---- read phase ----
        if (t > 0 && tid < 16) {
            float s = 0.0f;
            #pragma unroll
            for (int k = 0; k < 8; ++k) s += psum_s[cur][k][tid];
            out[(size_t)(b0 + tid) * TSEQ + (t - 1)] = fast_tanh(s + bout);
        }

        f32x4 giR_n, giZ_n, giN_n;
        if constexpr (USE_GI) {
            if (t + 1 < TSEQ) {
                const float* gp = gi + ((size_t)(t + 1) * NB + (b0 + bcol)) * 384
                                + w * 16 + g4 * 4;
                giR_n = *(const f32x4*)(gp);
                giZ_n = *(const f32x4*)(gp + 128);
                giN_n = *(const f32x4*)(gp + 256);
            }
        }

        f32x4 acc0, acc1, acc2, acc3 = biasNH;
        if constexpr (USE_GI) {
            acc0 = giR; acc1 = giZ; acc2 = giN;
        } else {
            acc0 = biasR; acc1 = biasZ; acc2 = biasNI;
            const float* xp = x + ((size_t)(b0 + bcol) * TSEQ + t) * FDIM;
            #pragma unroll
            for (int kt = 0; kt < 2; ++kt) {
                float4 a = *(const float4*)(xp + kt * 32 + g4 * 8);
                float4 b = *(const float4*)(xp + kt * 32 + g4 * 8 + 4);
                short8 xh, xl;
                pack8(a, b, xh, xl);
                acc0 = mfma16(Wih_lo[0][kt], xh, acc0);
                acc0 = mfma16(Wih_hi[0][kt], xl, acc0);
                acc0 = mfma16(Wih_hi[0][kt], xh, acc0);
                acc1 = mfma16(Wih_lo[1][kt], xh, acc1);
                acc1 = mfma16(Wih_hi[1][kt], xl, acc1);
                acc1 = mfma16(Wih_hi[1][kt], xh, acc1);
                acc2 = mfma16(Wih_lo[2][kt], xh, acc2);
                acc2 = mfma16(Wih_hi[2][kt], xl, acc2);
                acc2 = mfma16(Wih_hi[2][kt], xh, acc2);
            }
        }

        #pragma unroll
        for (int kt = 0; kt < 4; ++kt) {
            short8 bh = *(const short8*)&h_s[cur][bcol][kt * 32 + g4 * 8];
            acc0 = mfma16(Whh_lo[0][kt], bh, acc0);
            acc0 = mfma16(Whh_hi[0][kt], bh, acc0);
            acc1 = mfma16(Whh_lo[1][kt], bh, acc1);
            acc1 = mfma16(Whh_hi[1][kt], bh, acc1);
            acc3 = mfma16(Whh_lo[2][kt], bh, acc3);
            acc3 = mfma16(Whh_hi[2][kt], bh, acc3);
        }

        float psum = 0.0f;
        #pragma unroll
        for (int i = 0; i < 4; ++i) {
            float r  = fast_sig(acc0[i]);
            float z  = fast_sig(acc1[i]);
            float n  = fast_tanh(acc2[i] + r * acc3[i]);
            float hn = n + z * (h_old[i] - n);
            h_old[i] = hn;
            psum = fmaf(wout[i], hn, psum);
        }
        psum += __shfl_xor(psum, 16);
        psum += __shfl_xor(psum, 32);

        __syncthreads();   // barrier 1: all reads of cur buffers complete

        // ---- write phase ----
        {
            unsigned p0 = cvt_pk(h_old[0], h_old[1]);
            unsigned p1 = cvt_pk(h_old[2], h_old[3]);
            *(uint2*)&h_s[nxt][bcol][w * 16 + g4 * 4] = make_uint2(p0, p1);
        }
        if (lane < 16) psum_s[nxt][w][lane] = psum;

        if constexpr (USE_GI) { giR = giR_n; giZ = giZ_n; giN = giN_n; }

        __syncthreads();   // barrier 2: nxt buffers visible for next step
    }

    if (tid < 16) {
        float s = 0.0f;
        #pragma unroll
        for (int k = 0; k < 8; ++k) s += psum_s[0][k][tid];
        out[(size_t)(b0 + tid) * TSEQ + (TSEQ - 1)] = fast_tanh(s + bout);
    }
}

extern "C" void kernel_launch(void* const* d_in, const int* in_sizes, int n_in,
                              void* d_out, int out_size, void* d_ws, size_t ws_size,
                              hipStream_t stream) {
    const float* x     = (const float*)d_in[0];
    const float* W_ih  = (const float*)d_in[1];
    const float* W_hh  = (const float*)d_in[2];
    const float* b_ih  = (const float*)d_in[3];
    const float* b_hh  = (const float*)d_in[4];
    const float* W_out = (const float*)d_in[5];
    const float* b_out = (const float*)d_in[6];
    float* out = (float*)d_out;

    const size_t gi_bytes = (size_t)TSEQ * NB * 384 * sizeof(float);
    if (ws_size >= gi_bytes) {
        float* gi = (float*)d_ws;
        gi_gemm<<<dim3(32, 32), 512, 0, stream>>>(x, W_ih, b_ih, b_hh, gi);
        gru_rec<true><<<32, 512, 0, stream>>>(x, W_ih, W_hh, b_ih, b_hh,
                                              W_out, b_out, gi, out);
    } else {
        gru_rec<false><<<32, 512, 0, stream>>>(x, W_ih, W_hh, b_ih, b_hh,
                                               W_out, b_out, nullptr, out);
    }
}

// Round 5
// 674.322 us; speedup vs baseline: 1.5450x; 1.5450x over previous
//
#include <hip/hip_runtime.h>
#include <math.h>

#define TSEQ 512
#define FDIM 64
#define HDIM 128

typedef __attribute__((ext_vector_type(8))) short short8;
typedef __attribute__((ext_vector_type(4))) float f32x4;

__device__ __forceinline__ float fast_sig(float x) {
    return __builtin_amdgcn_rcpf(1.0f + __expf(-x));
}
__device__ __forceinline__ float fast_tanh(float x) {
    return 1.0f - 2.0f * __builtin_amdgcn_rcpf(1.0f + __expf(2.0f * x));
}
__device__ __forceinline__ unsigned short bf16_rn(float v) {
    unsigned u = __float_as_uint(v);
    u += 0x7FFF + ((u >> 16) & 1);
    return (unsigned short)(u >> 16);
}
__device__ __forceinline__ void cvt_hilo(float v, unsigned short& hi, unsigned short& lo) {
    hi = bf16_rn(v);
    lo = bf16_rn(v - __uint_as_float((unsigned)hi << 16));
}
__device__ __forceinline__ unsigned cvt_pk(float a, float b) {
    unsigned r;
    asm("v_cvt_pk_bf16_f32 %0, %1, %2" : "=v"(r) : "v"(a), "v"(b));
    return r;
}
__device__ __forceinline__ f32x4 mfma16(short8 a, short8 b, f32x4 c) {
    return __builtin_amdgcn_mfma_f32_16x16x32_bf16(a, b, c, 0, 0, 0);
}

union U8 { unsigned u[4]; short8 s; };

// 8 f32 -> hi/lo bf16 short8 pair (RNE, hi + residual)
__device__ __forceinline__ void pack8(float4 a, float4 b, short8& hi, short8& lo) {
    U8 H, L;
    H.u[0] = cvt_pk(a.x, a.y); H.u[1] = cvt_pk(a.z, a.w);
    H.u[2] = cvt_pk(b.x, b.y); H.u[3] = cvt_pk(b.z, b.w);
    L.u[0] = cvt_pk(a.x - __uint_as_float(H.u[0] << 16),
                    a.y - __uint_as_float(H.u[0] & 0xFFFF0000u));
    L.u[1] = cvt_pk(a.z - __uint_as_float(H.u[1] << 16),
                    a.w - __uint_as_float(H.u[1] & 0xFFFF0000u));
    L.u[2] = cvt_pk(b.x - __uint_as_float(H.u[2] << 16),
                    b.y - __uint_as_float(H.u[2] & 0xFFFF0000u));
    L.u[3] = cvt_pk(b.z - __uint_as_float(H.u[3] << 16),
                    b.w - __uint_as_float(H.u[3] & 0xFFFF0000u));
    hi = H.s; lo = L.s;
}

// 32 blocks x 16 batches, 768 threads = 12 waves (3/SIMD).
// Waves 0-7 (consumers): h-recurrence for h-rows [16w,16w+16), 24 MFMA/step.
// Waves 8-11 (producers): gi(t+1) = x(t+1)*W_ih + biases, 36 MFMA/wave/step,
// double-buffered into gi_s; x prefetched 2 steps ahead in registers.
// Step: [reads of cur bufs + compute] -> B1 -> [writes to nxt bufs] -> B2.
__global__ __launch_bounds__(768)
void gru_pc(const float* __restrict__ x,
            const float* __restrict__ W_ih,
            const float* __restrict__ W_hh,
            const float* __restrict__ b_ih,
            const float* __restrict__ b_hh,
            const float* __restrict__ W_out,
            const float* __restrict__ b_out,
            float* __restrict__ out)
{
    const int tid  = threadIdx.x;
    const int wid  = tid >> 6;        // 0..11
    const int lane = tid & 63;
    const int g4   = lane >> 4;       // k-group / row-group
    const int bcol = lane & 15;       // batch column
    const int b0   = blockIdx.x * 16;

    __shared__ __align__(16) short h_s[2][16][136];    // [buf][batch][h] (+8 pad)
    __shared__ __align__(16) float gi_s[2][16][388];   // [buf][batch][384 gates] (+4 pad)
    __shared__ float psum_s[2][8][16];
    __shared__ float bias_s[384];                      // r,z: bi+bh; n: bi only

    const float bout = b_out[0];

    if (tid < 384)
        bias_s[tid] = (tid < 256) ? (b_ih[tid] + b_hh[tid]) : b_ih[tid];
    {
        unsigned* hp = (unsigned*)&h_s[0][0][0];
        for (int i = tid; i < 16 * 136 / 2; i += 768) hp[i] = 0u;
    }

    if (wid < 8) {
        // ================= consumer =================
        const int w = wid;
        short8 Whh_hi[3][4], Whh_lo[3][4];
        #pragma unroll
        for (int kd = 0; kd < 3; ++kd) {
            const int g = kd * 128 + w * 16 + bcol;
            #pragma unroll
            for (int kt = 0; kt < 4; ++kt) {
                const float* pw = W_hh + g * HDIM + kt * 32 + g4 * 8;
                short8 hi8, lo8;
                #pragma unroll
                for (int e = 0; e < 8; ++e) {
                    unsigned short h_, l_;
                    cvt_hilo(pw[e], h_, l_);
                    hi8[e] = (short)h_; lo8[e] = (short)l_;
                }
                Whh_hi[kd][kt] = hi8; Whh_lo[kd][kt] = lo8;
            }
        }
        f32x4 biasNH;
        float wout_r[4], h_old[4];
        #pragma unroll
        for (int i = 0; i < 4; ++i) {
            const int gr = w * 16 + g4 * 4 + i;
            biasNH[i] = b_hh[256 + gr];
            wout_r[i] = W_out[gr];
            h_old[i]  = 0.0f;
        }
        __syncthreads();   // prologue barrier (gi(0), h zeros ready)

        for (int t = 0; t < TSEQ; ++t) {
            const int cur = t & 1, nxt = cur ^ 1;
            // ---- read phase ----
            f32x4 acc0 = *(const f32x4*)&gi_s[cur][bcol][      w * 16 + g4 * 4];
            f32x4 acc1 = *(const f32x4*)&gi_s[cur][bcol][128 + w * 16 + g4 * 4];
            f32x4 acc2 = *(const f32x4*)&gi_s[cur][bcol][256 + w * 16 + g4 * 4];
            f32x4 acc3 = biasNH;
            #pragma unroll
            for (int kt = 0; kt < 4; ++kt) {
                short8 bh = *(const short8*)&h_s[cur][bcol][kt * 32 + g4 * 8];
                acc0 = mfma16(Whh_lo[0][kt], bh, acc0);
                acc0 = mfma16(Whh_hi[0][kt], bh, acc0);
                acc1 = mfma16(Whh_lo[1][kt], bh, acc1);
                acc1 = mfma16(Whh_hi[1][kt], bh, acc1);
                acc3 = mfma16(Whh_lo[2][kt], bh, acc3);
                acc3 = mfma16(Whh_hi[2][kt], bh, acc3);
            }
            float psum = 0.0f;
            #pragma unroll
            for (int i = 0; i < 4; ++i) {
                float r  = fast_sig(acc0[i]);
                float z  = fast_sig(acc1[i]);
                float n  = fast_tanh(acc2[i] + r * acc3[i]);
                float hn = n + z * (h_old[i] - n);
                h_old[i] = hn;
                psum = fmaf(wout_r[i], hn, psum);
            }
            psum += __shfl_xor(psum, 16);
            psum += __shfl_xor(psum, 32);

            __syncthreads();   // B1: all reads of cur buffers complete
            // ---- write phase ----
            {
                unsigned p0 = cvt_pk(h_old[0], h_old[1]);
                unsigned p1 = cvt_pk(h_old[2], h_old[3]);
                *(uint2*)&h_s[nxt][bcol][w * 16 + g4 * 4] = make_uint2(p0, p1);
            }
            if (lane < 16) psum_s[nxt][w][lane] = psum;
            __syncthreads();   // B2: nxt buffers visible
        }
    } else {
        // ================= producer =================
        const int p = wid - 8;   // 0..3, owns gate rows [32p, 32p+32) per kind
        short8 Wih_hi[3][2][2], Wih_lo[3][2][2];   // [kind][j][kt]
        #pragma unroll
        for (int kd = 0; kd < 3; ++kd)
        #pragma unroll
        for (int j = 0; j < 2; ++j) {
            const int g = kd * 128 + p * 32 + j * 16 + bcol;
            #pragma unroll
            for (int kt = 0; kt < 2; ++kt) {
                const float* pw = W_ih + g * FDIM + kt * 32 + g4 * 8;
                short8 hi8, lo8;
                #pragma unroll
                for (int e = 0; e < 8; ++e) {
                    unsigned short h_, l_;
                    cvt_hilo(pw[e], h_, l_);
                    hi8[e] = (short)h_; lo8[e] = (short)l_;
                }
                Wih_hi[kd][j][kt] = hi8; Wih_lo[kd][j][kt] = lo8;
            }
        }
        const float* xb = x + (size_t)(b0 + bcol) * TSEQ * FDIM;
        float4 xA0, xA1, xA2, xA3;   // x(t+1) fragments, reused in place

        // ---- prologue: gi(0) with biases from global (bias_s not synced yet)
        {
            float4 a0 = *(const float4*)(xb + g4 * 8);
            float4 a1 = *(const float4*)(xb + g4 * 8 + 4);
            float4 a2 = *(const float4*)(xb + 32 + g4 * 8);
            float4 a3 = *(const float4*)(xb + 32 + g4 * 8 + 4);
            short8 xh[2], xl[2];
            pack8(a0, a1, xh[0], xl[0]);
            pack8(a2, a3, xh[1], xl[1]);
            f32x4 acc[3][2];
            #pragma unroll
            for (int kd = 0; kd < 3; ++kd)
            #pragma unroll
            for (int j = 0; j < 2; ++j) {
                #pragma unroll
                for (int i = 0; i < 4; ++i) {
                    const int gr = kd * 128 + p * 32 + j * 16 + g4 * 4 + i;
                    acc[kd][j][i] = (gr < 256) ? (b_ih[gr] + b_hh[gr]) : b_ih[gr];
                }
                #pragma unroll
                for (int kt = 0; kt < 2; ++kt) {
                    f32x4 a = acc[kd][j];
                    a = mfma16(Wih_lo[kd][j][kt], xh[kt], a);
                    a = mfma16(Wih_hi[kd][j][kt], xl[kt], a);
                    a = mfma16(Wih_hi[kd][j][kt], xh[kt], a);
                    acc[kd][j] = a;
                }
                *(f32x4*)&gi_s[0][bcol][kd * 128 + p * 32 + j * 16 + g4 * 4] = acc[kd][j];
            }
            // load x(1)
            xA0 = *(const float4*)(xb + FDIM + g4 * 8);
            xA1 = *(const float4*)(xb + FDIM + g4 * 8 + 4);
            xA2 = *(const float4*)(xb + FDIM + 32 + g4 * 8);
            xA3 = *(const float4*)(xb + FDIM + 32 + g4 * 8 + 4);
        }
        __syncthreads();   // prologue barrier

        for (int t = 0; t < TSEQ; ++t) {
            const int cur = t & 1, nxt = cur ^ 1;
            // ---- read phase ----
            if (p == 0 && lane < 16 && t > 0) {
                float s = 0.0f;
                #pragma unroll
                for (int k = 0; k < 8; ++k) s += psum_s[cur][k][lane];
                out[(size_t)(b0 + lane) * TSEQ + (t - 1)] = fast_tanh(s + bout);
            }
            const bool prod = (t + 1 < TSEQ);
            short8 xh[2], xl[2];
            if (prod) {                       // pack x(t+1) (regs from last step)
                pack8(xA0, xA1, xh[0], xl[0]);
                pack8(xA2, xA3, xh[1], xl[1]);
            }
            if (t + 2 < TSEQ) {               // reload regs with x(t+2)
                const float* xp = xb + (size_t)(t + 2) * FDIM;
                xA0 = *(const float4*)(xp + g4 * 8);
                xA1 = *(const float4*)(xp + g4 * 8 + 4);
                xA2 = *(const float4*)(xp + 32 + g4 * 8);
                xA3 = *(const float4*)(xp + 32 + g4 * 8 + 4);
            }
            f32x4 acc[3][2];
            if (prod) {
                #pragma unroll
                for (int kd = 0; kd < 3; ++kd)
                #pragma unroll
                for (int j = 0; j < 2; ++j) {
                    f32x4 a = *(const f32x4*)&bias_s[kd * 128 + p * 32 + j * 16 + g4 * 4];
                    #pragma unroll
                    for (int kt = 0; kt < 2; ++kt) {
                        a = mfma16(Wih_lo[kd][j][kt], xh[kt], a);
                        a = mfma16(Wih_hi[kd][j][kt], xl[kt], a);
                        a = mfma16(Wih_hi[kd][j][kt], xh[kt], a);
                    }
                    acc[kd][j] = a;
                }
            }
            __syncthreads();   // B1
            // ---- write phase ----
            if (prod) {
                #pragma unroll
                for (int kd = 0; kd < 3; ++kd)
                #pragma unroll
                for (int j = 0; j < 2; ++j)
                    *(f32x4*)&gi_s[nxt][bcol][kd * 128 + p * 32 + j * 16 + g4 * 4]
                        = acc[kd][j];
            }
            __syncthreads();   // B2
        }
        // final output (t = TSEQ-1); psum for t=511 landed in buffer 0
        if (p == 0 && lane < 16) {
            float s = 0.0f;
            #pragma unroll
            for (int k = 0; k < 8; ++k) s += psum_s[0][k][lane];
            out[(size_t)(b0 + lane) * TSEQ + (TSEQ - 1)] = fast_tanh(s + bout);
        }
    }
}

extern "C" void kernel_launch(void* const* d_in, const int* in_sizes, int n_in,
                              void* d_out, int out_size, void* d_ws, size_t ws_size,
                              hipStream_t stream) {
    const float* x     = (const float*)d_in[0];
    const float* W_ih  = (const float*)d_in[1];
    const float* W_hh  = (const float*)d_in[2];
    const float* b_ih  = (const float*)d_in[3];
    const float* b_hh  = (const float*)d_in[4];
    const float* W_out = (const float*)d_in[5];
    const float* b_out = (const float*)d_in[6];
    float* out = (float*)d_out;

    gru_pc<<<32, 768, 0, stream>>>(x, W_ih, W_hh, b_ih, b_hh, W_out, b_out, out);
}

// Round 6
// 646.746 us; speedup vs baseline: 1.6109x; 1.0426x over previous
//
#include <hip/hip_runtime.h>
#include <math.h>

#define TSEQ 512
#define FDIM 64
#define HDIM 128

typedef __attribute__((ext_vector_type(8))) short short8;
typedef __attribute__((ext_vector_type(4))) float f32x4;

// LDS geometry (element strides)
#define H_ROW 136              // shorts per batch row (+8 pad)
#define H_BUF (16 * H_ROW)
#define G_ROW 388              // floats per batch row (+4 pad)
#define G_BUF (16 * G_ROW)
#define P_ROW 10               // floats per batch row of psum (+2 pad)
#define P_BUF (16 * P_ROW)

__device__ __forceinline__ float fast_sig(float x) {
    return __builtin_amdgcn_rcpf(1.0f + __expf(-x));
}
__device__ __forceinline__ float fast_tanh(float x) {
    return 1.0f - 2.0f * __builtin_amdgcn_rcpf(1.0f + __expf(2.0f * x));
}
__device__ __forceinline__ unsigned short bf16_rn(float v) {
    unsigned u = __float_as_uint(v);
    u += 0x7FFF + ((u >> 16) & 1);
    return (unsigned short)(u >> 16);
}
__device__ __forceinline__ void cvt_hilo(float v, unsigned short& hi, unsigned short& lo) {
    hi = bf16_rn(v);
    lo = bf16_rn(v - __uint_as_float((unsigned)hi << 16));
}
__device__ __forceinline__ unsigned cvt_pk(float a, float b) {
    unsigned r;
    asm("v_cvt_pk_bf16_f32 %0, %1, %2" : "=v"(r) : "v"(a), "v"(b));
    return r;
}
__device__ __forceinline__ f32x4 mfma16(short8 a, short8 b, f32x4 c) {
    return __builtin_amdgcn_mfma_f32_16x16x32_bf16(a, b, c, 0, 0, 0);
}

union U8 { unsigned u[4]; short8 s; };

__device__ __forceinline__ void pack8(float4 a, float4 b, short8& hi, short8& lo) {
    U8 H, L;
    H.u[0] = cvt_pk(a.x, a.y); H.u[1] = cvt_pk(a.z, a.w);
    H.u[2] = cvt_pk(b.x, b.y); H.u[3] = cvt_pk(b.z, b.w);
    L.u[0] = cvt_pk(a.x - __uint_as_float(H.u[0] << 16),
                    a.y - __uint_as_float(H.u[0] & 0xFFFF0000u));
    L.u[1] = cvt_pk(a.z - __uint_as_float(H.u[1] << 16),
                    a.w - __uint_as_float(H.u[1] & 0xFFFF0000u));
    L.u[2] = cvt_pk(b.x - __uint_as_float(H.u[2] << 16),
                    b.y - __uint_as_float(H.u[2] & 0xFFFF0000u));
    L.u[3] = cvt_pk(b.z - __uint_as_float(H.u[3] << 16),
                    b.w - __uint_as_float(H.u[3] & 0xFFFF0000u));
    hi = H.s; lo = L.s;
}

// Raw workgroup barrier: drain LDS only. Global loads/stores stay in flight
// across the barrier (no vmcnt(0) drain as __syncthreads would force).
__device__ __forceinline__ void wg_barrier() {
    __builtin_amdgcn_sched_barrier(0);
    asm volatile("s_waitcnt lgkmcnt(0)" ::: "memory");
    __builtin_amdgcn_s_barrier();
    asm volatile("" ::: "memory");
    __builtin_amdgcn_sched_barrier(0);
}

// 32 blocks x 16 batches, 768 threads = 12 waves (3/SIMD, pinned by
// __launch_bounds__(768,3) so stationary weights stay in VGPRs).
// Waves 0-7  (consumers): h-recurrence, 24 MFMA/step, gates in-register.
// Waves 8-11 (producers): gi(t+1) = x(t+1)*W_ih + biases into LDS; wave p1
//                         additionally finalizes out[t-1] and stores a
//                         float4 of outputs every 4 steps.
// Triple-buffered h/gi/psum with ONE raw barrier per step:
//   step s: read buf rb=s%3, write buf wb=(s+1)%3, barrier.
// (2-buffer/1-barrier races WAR across one barrier; 3 buffers are safe:
//  a wave at s+1 writes (s+2)%3 which was last read at s-1, fully drained.)
__global__ __launch_bounds__(768, 3)
void gru_pc2(const float* __restrict__ x,
             const float* __restrict__ W_ih,
             const float* __restrict__ W_hh,
             const float* __restrict__ b_ih,
             const float* __restrict__ b_hh,
             const float* __restrict__ W_out,
             const float* __restrict__ b_out,
             float* __restrict__ out)
{
    const int tid  = threadIdx.x;
    const int wid  = tid >> 6;
    const int lane = tid & 63;
    const int g4   = lane >> 4;
    const int bcol = lane & 15;
    const int b0   = blockIdx.x * 16;

    __shared__ __align__(16) short h_s[3 * H_BUF];
    __shared__ __align__(16) float gi_s[3 * G_BUF];
    __shared__ __align__(16) float ps_s[3 * P_BUF];
    __shared__ float bias_s[384];

    const float bout = b_out[0];

    if (tid < 384)
        bias_s[tid] = (tid < 256) ? (b_ih[tid] + b_hh[tid]) : b_ih[tid];
    {   // zero h buffer 0 (read at t=0)
        unsigned* hp = (unsigned*)h_s;
        for (int i = tid; i < H_BUF / 2; i += 768) hp[i] = 0u;
    }

    // ================= per-role setup (pre-barrier) =================
    short8 Whh_hi[3][4], Whh_lo[3][4];           // consumer weights
    short8 Wih_hi[3][2][2], Wih_lo[3][2][2];     // producer weights
    f32x4  biasNH;
    float  wout_r[4], h_old[4];
    float4 xA0, xA1, xA2, xA3;
    const int p = wid - 8;

    if (wid < 8) {
        const int w = wid;
        #pragma unroll
        for (int kd = 0; kd < 3; ++kd) {
            const int g = kd * 128 + w * 16 + bcol;
            #pragma unroll
            for (int kt = 0; kt < 4; ++kt) {
                const float* pw = W_hh + g * HDIM + kt * 32 + g4 * 8;
                short8 hi8, lo8;
                #pragma unroll
                for (int e = 0; e < 8; ++e) {
                    unsigned short h_, l_;
                    cvt_hilo(pw[e], h_, l_);
                    hi8[e] = (short)h_; lo8[e] = (short)l_;
                }
                Whh_hi[kd][kt] = hi8; Whh_lo[kd][kt] = lo8;
            }
        }
        #pragma unroll
        for (int i = 0; i < 4; ++i) {
            const int gr = w * 16 + g4 * 4 + i;
            biasNH[i] = b_hh[256 + gr];
            wout_r[i] = W_out[gr];
            h_old[i]  = 0.0f;
        }
    } else {
        #pragma unroll
        for (int kd = 0; kd < 3; ++kd)
        #pragma unroll
        for (int j = 0; j < 2; ++j) {
            const int g = kd * 128 + p * 32 + j * 16 + bcol;
            #pragma unroll
            for (int kt = 0; kt < 2; ++kt) {
                const float* pw = W_ih + g * FDIM + kt * 32 + g4 * 8;
                short8 hi8, lo8;
                #pragma unroll
                for (int e = 0; e < 8; ++e) {
                    unsigned short h_, l_;
                    cvt_hilo(pw[e], h_, l_);
                    hi8[e] = (short)h_; lo8[e] = (short)l_;
                }
                Wih_hi[kd][j][kt] = hi8; Wih_lo[kd][j][kt] = lo8;
            }
        }
        // prologue: gi(0) into GI buffer 0, biases from global
        const float* xb = x + (size_t)(b0 + bcol) * TSEQ * FDIM;
        {
            float4 a0 = *(const float4*)(xb + g4 * 8);
            float4 a1 = *(const float4*)(xb + g4 * 8 + 4);
            float4 a2 = *(const float4*)(xb + 32 + g4 * 8);
            float4 a3 = *(const float4*)(xb + 32 + g4 * 8 + 4);
            short8 xh[2], xl[2];
            pack8(a0, a1, xh[0], xl[0]);
            pack8(a2, a3, xh[1], xl[1]);
            #pragma unroll
            for (int kd = 0; kd < 3; ++kd)
            #pragma unroll
            for (int j = 0; j < 2; ++j) {
                f32x4 a;
                #pragma unroll
                for (int i = 0; i < 4; ++i) {
                    const int gr = kd * 128 + p * 32 + j * 16 + g4 * 4 + i;
                    a[i] = (gr < 256) ? (b_ih[gr] + b_hh[gr]) : b_ih[gr];
                }
                #pragma unroll
                for (int kt = 0; kt < 2; ++kt) {
                    a = mfma16(Wih_lo[kd][j][kt], xh[kt], a);
                    a = mfma16(Wih_hi[kd][j][kt], xl[kt], a);
                    a = mfma16(Wih_hi[kd][j][kt], xh[kt], a);
                }
                *(f32x4*)&gi_s[0 * G_BUF + bcol * G_ROW
                               + kd * 128 + p * 32 + j * 16 + g4 * 4] = a;
            }
            xA0 = *(const float4*)(xb + FDIM + g4 * 8);
            xA1 = *(const float4*)(xb + FDIM + g4 * 8 + 4);
            xA2 = *(const float4*)(xb + FDIM + 32 + g4 * 8);
            xA3 = *(const float4*)(xb + FDIM + 32 + g4 * 8 + 4);
        }
    }

    __syncthreads();   // single uniform prologue barrier

    // ================= main loop =================
    if (wid < 8) {
        // ---------------- consumer ----------------
        const int w = wid;
        int rb = 0, wb = 1;
        for (int t = 0; t < TSEQ; t += 4) {
            #pragma unroll
            for (int u = 0; u < 4; ++u) {
                const int hro = rb * H_BUF + bcol * H_ROW;
                const int gro = rb * G_BUF + bcol * G_ROW + w * 16 + g4 * 4;
                f32x4 a0 = *(const f32x4*)&gi_s[gro];
                f32x4 a1 = *(const f32x4*)&gi_s[gro + 128];
                f32x4 a2 = *(const f32x4*)&gi_s[gro + 256];
                f32x4 a3 = biasNH;
                #pragma unroll
                for (int kt = 0; kt < 4; ++kt) {
                    short8 bh = *(const short8*)&h_s[hro + kt * 32 + g4 * 8];
                    a0 = mfma16(Whh_lo[0][kt], bh, a0);
                    a0 = mfma16(Whh_hi[0][kt], bh, a0);
                    a1 = mfma16(Whh_lo[1][kt], bh, a1);
                    a1 = mfma16(Whh_hi[1][kt], bh, a1);
                    a3 = mfma16(Whh_lo[2][kt], bh, a3);
                    a3 = mfma16(Whh_hi[2][kt], bh, a3);
                }
                float psum = 0.0f;
                #pragma unroll
                for (int i = 0; i < 4; ++i) {
                    float r  = fast_sig(a0[i]);
                    float z  = fast_sig(a1[i]);
                    float n  = fast_tanh(a2[i] + r * a3[i]);
                    float hn = n + z * (h_old[i] - n);
                    h_old[i] = hn;
                    psum = fmaf(wout_r[i], hn, psum);
                }
                psum += __shfl_xor(psum, 16);
                psum += __shfl_xor(psum, 32);
                {
                    unsigned p0_ = cvt_pk(h_old[0], h_old[1]);
                    unsigned p1_ = cvt_pk(h_old[2], h_old[3]);
                    *(uint2*)&h_s[wb * H_BUF + bcol * H_ROW + w * 16 + g4 * 4]
                        = make_uint2(p0_, p1_);
                }
                if (lane < 16) ps_s[wb * P_BUF + lane * P_ROW + w] = psum;
                wg_barrier();
                rb = wb; wb = (wb == 2) ? 0 : wb + 1;
            }
        }
    } else {
        // ---------------- producer ----------------
        const float* xb = x + (size_t)(b0 + bcol) * TSEQ * FDIM;
        const bool outw = (p == 1) && (lane < 16);
        float* outp = out + (size_t)(b0 + (lane & 15)) * TSEQ;
        float o0 = 0.f, o1 = 0.f, o2 = 0.f, o3 = 0.f;
        int rb = 0, wb = 1;
        for (int t = 0; t < TSEQ; t += 4) {
            #pragma unroll
            for (int u = 0; u < 4; ++u) {
                const int s = t + u;
                // ---- out path (p1, lanes 0-15): out[s-1] from psum(s-1) ----
                if (outw && s > 0) {
                    const int pro = rb * P_BUF + bcol * P_ROW;
                    f32x4 q0 = *(const f32x4*)&ps_s[pro];
                    f32x4 q1 = *(const f32x4*)&ps_s[pro + 4];
                    float sm = (q0[0] + q0[1]) + (q0[2] + q0[3])
                             + (q1[0] + q1[1]) + (q1[2] + q1[3]);
                    float val = fast_tanh(sm + bout);
                    if (u == 0) {
                        o3 = val;
                        *(float4*)(outp + (t - 4)) = make_float4(o0, o1, o2, o3);
                    } else if (u == 1) o0 = val;
                    else if (u == 2) o1 = val;
                    else o2 = val;
                }
                // ---- gi(s+1) production ----
                const bool prod = (s + 1 < TSEQ);
                short8 xh[2], xl[2];
                if (prod) {
                    pack8(xA0, xA1, xh[0], xl[0]);
                    pack8(xA2, xA3, xh[1], xl[1]);
                }
                if (s + 2 < TSEQ) {
                    const float* xp = xb + (size_t)(s + 2) * FDIM;
                    xA0 = *(const float4*)(xp + g4 * 8);
                    xA1 = *(const float4*)(xp + g4 * 8 + 4);
                    xA2 = *(const float4*)(xp + 32 + g4 * 8);
                    xA3 = *(const float4*)(xp + 32 + g4 * 8 + 4);
                }
                if (prod) {
                    #pragma unroll
                    for (int kd = 0; kd < 3; ++kd)
                    #pragma unroll
                    for (int j = 0; j < 2; ++j) {
                        const int go = kd * 128 + p * 32 + j * 16 + g4 * 4;
                        f32x4 a = *(const f32x4*)&bias_s[go];
                        #pragma unroll
                        for (int kt = 0; kt < 2; ++kt) {
                            a = mfma16(Wih_lo[kd][j][kt], xh[kt], a);
                            a = mfma16(Wih_hi[kd][j][kt], xl[kt], a);
                            a = mfma16(Wih_hi[kd][j][kt], xh[kt], a);
                        }
                        *(f32x4*)&gi_s[wb * G_BUF + bcol * G_ROW + go] = a;
                    }
                }
                wg_barrier();
                rb = wb; wb = (wb == 2) ? 0 : wb + 1;
            }
        }
        // tail: out[511] from psum(511) in PS[512%3 == 2]
        if (outw) {
            const int pro = 2 * P_BUF + bcol * P_ROW;
            f32x4 q0 = *(const f32x4*)&ps_s[pro];
            f32x4 q1 = *(const f32x4*)&ps_s[pro + 4];
            float sm = (q0[0] + q0[1]) + (q0[2] + q0[3])
                     + (q1[0] + q1[1]) + (q1[2] + q1[3]);
            o3 = fast_tanh(sm + bout);
            *(float4*)(outp + (TSEQ - 4)) = make_float4(o0, o1, o2, o3);
        }
    }
}

extern "C" void kernel_launch(void* const* d_in, const int* in_sizes, int n_in,
                              void* d_out, int out_size, void* d_ws, size_t ws_size,
                              hipStream_t stream) {
    const float* x     = (const float*)d_in[0];
    const float* W_ih  = (const float*)d_in[1];
    const float* W_hh  = (const float*)d_in[2];
    const float* b_ih  = (const float*)d_in[3];
    const float* b_hh  = (const float*)d_in[4];
    const float* W_out = (const float*)d_in[5];
    const float* b_out = (const float*)d_in[6];
    float* out = (float*)d_out;

    gru_pc2<<<32, 768, 0, stream>>>(x, W_ih, W_hh, b_ih, b_hh, W_out, b_out, out);
}

// Round 7
// 636.607 us; speedup vs baseline: 1.6365x; 1.0159x over previous
//
#include <hip/hip_runtime.h>
#include <math.h>

#define TSEQ 512
#define FDIM 64
#define HDIM 128

typedef __attribute__((ext_vector_type(8))) short short8;
typedef __attribute__((ext_vector_type(4))) float f32x4;

#define H_ROW 136                 // shorts per batch row (+8 pad)
#define H_BUF (16 * H_ROW)

__device__ __forceinline__ float fast_sig(float x) {
    return __builtin_amdgcn_rcpf(1.0f + __expf(-x));
}
__device__ __forceinline__ float fast_tanh(float x) {
    return 1.0f - 2.0f * __builtin_amdgcn_rcpf(1.0f + __expf(2.0f * x));
}
__device__ __forceinline__ unsigned short bf16_rn(float v) {
    unsigned u = __float_as_uint(v);
    u += 0x7FFF + ((u >> 16) & 1);
    return (unsigned short)(u >> 16);
}
__device__ __forceinline__ void cvt_hilo(float v, unsigned short& hi, unsigned short& lo) {
    hi = bf16_rn(v);
    lo = bf16_rn(v - __uint_as_float((unsigned)hi << 16));
}
__device__ __forceinline__ unsigned cvt_pk(float a, float b) {
    unsigned r;
    asm("v_cvt_pk_bf16_f32 %0, %1, %2" : "=v"(r) : "v"(a), "v"(b));
    return r;
}
__device__ __forceinline__ f32x4 mfma16(short8 a, short8 b, f32x4 c) {
    return __builtin_amdgcn_mfma_f32_16x16x32_bf16(a, b, c, 0, 0, 0);
}

union U8 { unsigned u[4]; short8 s; };

__device__ __forceinline__ void pack8(float4 a, float4 b, short8& hi, short8& lo) {
    U8 H, L;
    H.u[0] = cvt_pk(a.x, a.y); H.u[1] = cvt_pk(a.z, a.w);
    H.u[2] = cvt_pk(b.x, b.y); H.u[3] = cvt_pk(b.z, b.w);
    L.u[0] = cvt_pk(a.x - __uint_as_float(H.u[0] << 16),
                    a.y - __uint_as_float(H.u[0] & 0xFFFF0000u));
    L.u[1] = cvt_pk(a.z - __uint_as_float(H.u[1] << 16),
                    a.w - __uint_as_float(H.u[1] & 0xFFFF0000u));
    L.u[2] = cvt_pk(b.x - __uint_as_float(H.u[2] << 16),
                    b.y - __uint_as_float(H.u[2] & 0xFFFF0000u));
    L.u[3] = cvt_pk(b.z - __uint_as_float(H.u[3] << 16),
                    b.w - __uint_as_float(H.u[3] & 0xFFFF0000u));
    hi = H.s; lo = L.s;
}

// Raw barrier: drain LDS only; global loads/stores stay in flight.
__device__ __forceinline__ void wg_barrier() {
    __builtin_amdgcn_sched_barrier(0);
    asm volatile("s_waitcnt lgkmcnt(0)" ::: "memory");
    __builtin_amdgcn_s_barrier();
    asm volatile("" ::: "memory");
    __builtin_amdgcn_sched_barrier(0);
}

// 32 blocks x 16 batches, 512 threads = 8 waves (2/SIMD).
// UNIFIED waves: wave w owns gate rows [16w,16w+16) of r,z,n and computes
// both the x-projection (from global-prefetched, reg-converted x fragments;
// no LDS) and the h-recurrence (h via LDS, bf16-hi, 4 ds_read_b128/wave).
// Per-CU LDS traffic/step: ~50 wave-instrs (vs ~122 in the split design).
// Triple-buffered h/psum, one lgkm-only barrier per step (R6-proven).
// Wave 0 lanes 0-15 additionally finalize out with a 4-step float4 buffer.
__global__ __launch_bounds__(512, 2)
void gru_uni(const float* __restrict__ x,
             const float* __restrict__ W_ih,
             const float* __restrict__ W_hh,
             const float* __restrict__ b_ih,
             const float* __restrict__ b_hh,
             const float* __restrict__ W_out,
             const float* __restrict__ b_out,
             float* __restrict__ out)
{
    const int tid  = threadIdx.x;
    const int wid  = tid >> 6;        // 0..7
    const int lane = tid & 63;
    const int g4   = lane >> 4;
    const int bcol = lane & 15;
    const int b0   = blockIdx.x * 16;

    __shared__ __align__(16) short h_s[3][16][H_ROW];
    __shared__ __align__(16) float ps_s[3][16][12];   // [buf][batch][wave]+pad

    // ---- stationary weights (hi/lo bf16) ----
    short8 Whh_hi[3][4], Whh_lo[3][4];
    short8 Wih_hi[3][2], Wih_lo[3][2];
    #pragma unroll
    for (int kd = 0; kd < 3; ++kd) {
        const int g = kd * 128 + wid * 16 + bcol;
        #pragma unroll
        for (int kt = 0; kt < 4; ++kt) {
            const float* pw = W_hh + g * HDIM + kt * 32 + g4 * 8;
            short8 hi8, lo8;
            #pragma unroll
            for (int e = 0; e < 8; ++e) {
                unsigned short h_, l_;
                cvt_hilo(pw[e], h_, l_);
                hi8[e] = (short)h_; lo8[e] = (short)l_;
            }
            Whh_hi[kd][kt] = hi8; Whh_lo[kd][kt] = lo8;
        }
        #pragma unroll
        for (int kt = 0; kt < 2; ++kt) {
            const float* pw = W_ih + g * FDIM + kt * 32 + g4 * 8;
            short8 hi8, lo8;
            #pragma unroll
            for (int e = 0; e < 8; ++e) {
                unsigned short h_, l_;
                cvt_hilo(pw[e], h_, l_);
                hi8[e] = (short)h_; lo8[e] = (short)l_;
            }
            Wih_hi[kd][kt] = hi8; Wih_lo[kd][kt] = lo8;
        }
    }

    f32x4 biasR, biasZ, biasNI, biasNH;
    float wout_r[4], h_old[4];
    #pragma unroll
    for (int i = 0; i < 4; ++i) {
        const int gr = wid * 16 + g4 * 4 + i;
        biasR[i]  = b_ih[gr]       + b_hh[gr];
        biasZ[i]  = b_ih[128 + gr] + b_hh[128 + gr];
        biasNI[i] = b_ih[256 + gr];
        biasNH[i] = b_hh[256 + gr];
        wout_r[i] = W_out[gr];
        h_old[i]  = 0.0f;
    }
    const float bout = b_out[0];

    {   // zero h buffer 0
        unsigned* hp = (unsigned*)&h_s[0][0][0];
        for (int i = tid; i < H_BUF / 2; i += 512) hp[i] = 0u;
    }

    // ---- x pipeline: 2 slots, loads issued 2 steps ahead ----
    const float* xb = x + (size_t)(b0 + bcol) * TSEQ * FDIM;
    float4 sA0, sA1, sA2, sA3, sB0, sB1, sB2, sB3;
    sA0 = *(const float4*)(xb + g4 * 8);
    sA1 = *(const float4*)(xb + g4 * 8 + 4);
    sA2 = *(const float4*)(xb + 32 + g4 * 8);
    sA3 = *(const float4*)(xb + 32 + g4 * 8 + 4);
    {
        const float* xp1 = xb + FDIM;
        sB0 = *(const float4*)(xp1 + g4 * 8);
        sB1 = *(const float4*)(xp1 + g4 * 8 + 4);
        sB2 = *(const float4*)(xp1 + 32 + g4 * 8);
        sB3 = *(const float4*)(xp1 + 32 + g4 * 8 + 4);
    }
    short8 xfh0, xfl0, xfh1, xfl1;          // fragments of x(t) for this step
    pack8(sA0, sA1, xfh0, xfl0);
    pack8(sA2, sA3, xfh1, xfl1);

    __syncthreads();   // prologue barrier

    const bool outw = (wid == 0) && (lane < 16);
    float* outp = out + (size_t)(b0 + lane) * TSEQ;
    float o0 = 0.f, o1 = 0.f, o2 = 0.f, o3 = 0.f;
    int rb = 0, wb = 1;

    for (int t = 0; t < TSEQ; t += 4) {
        #pragma unroll
        for (int u = 0; u < 4; ++u) {
            const int s = t + u;

            // ---- out path: out[s-1] from psum(s-1) (in buffer rb) ----
            if (outw && s > 0) {
                f32x4 q0 = *(const f32x4*)&ps_s[rb][lane][0];
                f32x4 q1 = *(const f32x4*)&ps_s[rb][lane][4];
                float sm = (q0[0] + q0[1]) + (q0[2] + q0[3])
                         + (q1[0] + q1[1]) + (q1[2] + q1[3]);
                float val = fast_tanh(sm + bout);
                if (u == 0) {
                    o3 = val;
                    *(float4*)(outp + (t - 4)) = make_float4(o0, o1, o2, o3);
                } else if (u == 1) o0 = val;
                else if (u == 2) o1 = val;
                else o2 = val;
            }

            // ---- issue x(s+2) load into the free slot (clamped index) ----
            {
                const int tl = (s + 2 < TSEQ) ? (s + 2) : (TSEQ - 1);
                const float* xp = xb + (size_t)tl * FDIM;
                if ((u & 1) == 0) {
                    sA0 = *(const float4*)(xp + g4 * 8);
                    sA1 = *(const float4*)(xp + g4 * 8 + 4);
                    sA2 = *(const float4*)(xp + 32 + g4 * 8);
                    sA3 = *(const float4*)(xp + 32 + g4 * 8 + 4);
                } else {
                    sB0 = *(const float4*)(xp + g4 * 8);
                    sB1 = *(const float4*)(xp + g4 * 8 + 4);
                    sB2 = *(const float4*)(xp + 32 + g4 * 8);
                    sB3 = *(const float4*)(xp + 32 + g4 * 8 + 4);
                }
            }

            // ---- h fragments (LDS) ----
            short8 bh0 = *(const short8*)&h_s[rb][bcol][0 * 32 + g4 * 8];
            short8 bh1 = *(const short8*)&h_s[rb][bcol][1 * 32 + g4 * 8];
            short8 bh2 = *(const short8*)&h_s[rb][bcol][2 * 32 + g4 * 8];
            short8 bh3 = *(const short8*)&h_s[rb][bcol][3 * 32 + g4 * 8];

            f32x4 a0 = biasR, a1 = biasZ, a2 = biasNI, a3 = biasNH;

            // x-part (register fragments, no LDS dependency)
            a0 = mfma16(Wih_lo[0][0], xfh0, a0);
            a0 = mfma16(Wih_hi[0][0], xfl0, a0);
            a0 = mfma16(Wih_hi[0][0], xfh0, a0);
            a0 = mfma16(Wih_lo[0][1], xfh1, a0);
            a0 = mfma16(Wih_hi[0][1], xfl1, a0);
            a0 = mfma16(Wih_hi[0][1], xfh1, a0);
            a1 = mfma16(Wih_lo[1][0], xfh0, a1);
            a1 = mfma16(Wih_hi[1][0], xfl0, a1);
            a1 = mfma16(Wih_hi[1][0], xfh0, a1);
            a1 = mfma16(Wih_lo[1][1], xfh1, a1);
            a1 = mfma16(Wih_hi[1][1], xfl1, a1);
            a1 = mfma16(Wih_hi[1][1], xfh1, a1);
            a2 = mfma16(Wih_lo[2][0], xfh0, a2);
            a2 = mfma16(Wih_hi[2][0], xfl0, a2);
            a2 = mfma16(Wih_hi[2][0], xfh0, a2);
            a2 = mfma16(Wih_lo[2][1], xfh1, a2);
            a2 = mfma16(Wih_hi[2][1], xfl1, a2);
            a2 = mfma16(Wih_hi[2][1], xfh1, a2);

            // h-part (2-term)
            a0 = mfma16(Whh_lo[0][0], bh0, a0); a0 = mfma16(Whh_hi[0][0], bh0, a0);
            a0 = mfma16(Whh_lo[0][1], bh1, a0); a0 = mfma16(Whh_hi[0][1], bh1, a0);
            a0 = mfma16(Whh_lo[0][2], bh2, a0); a0 = mfma16(Whh_hi[0][2], bh2, a0);
            a0 = mfma16(Whh_lo[0][3], bh3, a0); a0 = mfma16(Whh_hi[0][3], bh3, a0);
            a1 = mfma16(Whh_lo[1][0], bh0, a1); a1 = mfma16(Whh_hi[1][0], bh0, a1);
            a1 = mfma16(Whh_lo[1][1], bh1, a1); a1 = mfma16(Whh_hi[1][1], bh1, a1);
            a1 = mfma16(Whh_lo[1][2], bh2, a1); a1 = mfma16(Whh_hi[1][2], bh2, a1);
            a1 = mfma16(Whh_lo[1][3], bh3, a1); a1 = mfma16(Whh_hi[1][3], bh3, a1);
            a3 = mfma16(Whh_lo[2][0], bh0, a3); a3 = mfma16(Whh_hi[2][0], bh0, a3);
            a3 = mfma16(Whh_lo[2][1], bh1, a3); a3 = mfma16(Whh_hi[2][1], bh1, a3);
            a3 = mfma16(Whh_lo[2][2], bh2, a3); a3 = mfma16(Whh_hi[2][2], bh2, a3);
            a3 = mfma16(Whh_lo[2][3], bh3, a3); a3 = mfma16(Whh_hi[2][3], bh3, a3);

            // ---- gates (in-register) ----
            float psum = 0.0f;
            #pragma unroll
            for (int i = 0; i < 4; ++i) {
                float r  = fast_sig(a0[i]);
                float z  = fast_sig(a1[i]);
                float n  = fast_tanh(a2[i] + r * a3[i]);
                float hn = n + z * (h_old[i] - n);
                h_old[i] = hn;
                psum = fmaf(wout_r[i], hn, psum);
            }
            psum += __shfl_xor(psum, 16);
            psum += __shfl_xor(psum, 32);

            // ---- writes to wb ----
            {
                unsigned p0_ = cvt_pk(h_old[0], h_old[1]);
                unsigned p1_ = cvt_pk(h_old[2], h_old[3]);
                *(uint2*)&h_s[wb][bcol][wid * 16 + g4 * 4] = make_uint2(p0_, p1_);
            }
            if (lane < 16) ps_s[wb][lane][wid] = psum;

            // ---- convert x(s+1) fragments from the other slot ----
            if ((u & 1) == 0) {
                pack8(sB0, sB1, xfh0, xfl0);
                pack8(sB2, sB3, xfh1, xfl1);
            } else {
                pack8(sA0, sA1, xfh0, xfl0);
                pack8(sA2, sA3, xfh1, xfl1);
            }

            wg_barrier();
            rb = wb; wb = (wb == 2) ? 0 : wb + 1;
        }
    }

    // tail: out[511] from psum(511), written to buffer (512 % 3) == 2
    if (outw) {
        f32x4 q0 = *(const f32x4*)&ps_s[2][lane][0];
        f32x4 q1 = *(const f32x4*)&ps_s[2][lane][4];
        float sm = (q0[0] + q0[1]) + (q0[2] + q0[3])
                 + (q1[0] + q1[1]) + (q1[2] + q1[3]);
        o3 = fast_tanh(sm + bout);
        *(float4*)(outp + (TSEQ - 4)) = make_float4(o0, o1, o2, o3);
    }
}

extern "C" void kernel_launch(void* const* d_in, const int* in_sizes, int n_in,
                              void* d_out, int out_size, void* d_ws, size_t ws_size,
                              hipStream_t stream) {
    const float* x     = (const float*)d_in[0];
    const float* W_ih  = (const float*)d_in[1];
    const float* W_hh  = (const float*)d_in[2];
    const float* b_ih  = (const float*)d_in[3];
    const float* b_hh  = (const float*)d_in[4];
    const float* W_out = (const float*)d_in[5];
    const float* b_out = (const float*)d_in[6];
    float* out = (float*)d_out;

    gru_uni<<<32, 512, 0, stream>>>(x, W_ih, W_hh, b_ih, b_hh, W_out, b_out, out);
}

// Round 9
// 461.844 us; speedup vs baseline: 2.2558x; 1.3784x over previous
//
#include <hip/hip_runtime.h>
#include <math.h>

#define TSEQ 512
#define FDIM 64
#define HDIM 128

typedef _Float16 f16x8 __attribute__((ext_vector_type(8)));
typedef __fp16  fp16x2 __attribute__((ext_vector_type(2)));
typedef __attribute__((ext_vector_type(4))) float f32x4;

#define H_ROW 136                 // halves per batch row (+8 pad)
#define H_BUF (16 * H_ROW)

__device__ __forceinline__ float fast_sig(float x) {
    return __builtin_amdgcn_rcpf(1.0f + __expf(-x));
}
__device__ __forceinline__ float fast_tanh(float x) {
    return 1.0f - 2.0f * __builtin_amdgcn_rcpf(1.0f + __expf(2.0f * x));
}
__device__ __forceinline__ f32x4 mfma16f(f16x8 a, f16x8 b, f32x4 c) {
    return __builtin_amdgcn_mfma_f32_16x16x32_f16(a, b, c, 0, 0, 0);
}

union PU { fp16x2 h2[4]; f16x8 v; };

// 16 f32 (two float4) -> one f16x8 fragment (RTZ pack, x path)
__device__ __forceinline__ f16x8 pack_f16(float4 a, float4 b) {
    PU u;
    u.h2[0] = __builtin_amdgcn_cvt_pkrtz(a.x, a.y);
    u.h2[1] = __builtin_amdgcn_cvt_pkrtz(a.z, a.w);
    u.h2[2] = __builtin_amdgcn_cvt_pkrtz(b.x, b.y);
    u.h2[3] = __builtin_amdgcn_cvt_pkrtz(b.z, b.w);
    return u.v;
}

// Raw barrier: drain LDS only; global loads/stores stay in flight.
__device__ __forceinline__ void wg_barrier() {
    __builtin_amdgcn_sched_barrier(0);
    asm volatile("s_waitcnt lgkmcnt(0)" ::: "memory");
    __builtin_amdgcn_s_barrier();
    asm volatile("" ::: "memory");
    __builtin_amdgcn_sched_barrier(0);
}

// 32 blocks x 16 batches, 512 threads = 8 waves (2/SIMD).
// FP16 single-term numerics: weights/h/x in fp16 (2^-11 rel err), f32 MFMA
// accumulate. 18 MFMA/wave/step. Register demand ~170/lane so the stationary
// weights live in VGPRs (R7's ~254-reg demand forced ~128 regs into AGPRs and
// the allocator copied them back every step: ~190 phantom VALU/wave/step).
// Triple-buffered h/psum + one lgkm-only barrier per step (R6/R7-proven).
__global__ __launch_bounds__(512, 2)
void gru_f16(const float* __restrict__ x,
             const float* __restrict__ W_ih,
             const float* __restrict__ W_hh,
             const float* __restrict__ b_ih,
             const float* __restrict__ b_hh,
             const float* __restrict__ W_out,
             const float* __restrict__ b_out,
             float* __restrict__ out)
{
    const int tid  = threadIdx.x;
    const int wid  = tid >> 6;        // 0..7
    const int lane = tid & 63;
    const int g4   = lane >> 4;
    const int bcol = lane & 15;
    const int b0   = blockIdx.x * 16;

    __shared__ __align__(16) _Float16 h_s[3][16][H_ROW];
    __shared__ __align__(16) float ps_s[3][16][12];   // [buf][batch][wave]+pad

    // ---- stationary fp16 weights (RNE scalar converts, one-time) ----
    f16x8 WhhF[3][4];   // [kind r/z/n][kt]
    f16x8 WihF[3][2];
    #pragma unroll
    for (int kd = 0; kd < 3; ++kd) {
        const int g = kd * 128 + wid * 16 + bcol;
        #pragma unroll
        for (int kt = 0; kt < 4; ++kt) {
            const float* pw = W_hh + g * HDIM + kt * 32 + g4 * 8;
            f16x8 v;
            #pragma unroll
            for (int e = 0; e < 8; ++e) v[e] = (_Float16)pw[e];
            WhhF[kd][kt] = v;
        }
        #pragma unroll
        for (int kt = 0; kt < 2; ++kt) {
            const float* pw = W_ih + g * FDIM + kt * 32 + g4 * 8;
            f16x8 v;
            #pragma unroll
            for (int e = 0; e < 8; ++e) v[e] = (_Float16)pw[e];
            WihF[kd][kt] = v;
        }
    }

    f32x4 biasR, biasZ, biasNI, biasNH;
    float wout_r[4], h_old[4];
    #pragma unroll
    for (int i = 0; i < 4; ++i) {
        const int gr = wid * 16 + g4 * 4 + i;
        biasR[i]  = b_ih[gr]       + b_hh[gr];
        biasZ[i]  = b_ih[128 + gr] + b_hh[128 + gr];
        biasNI[i] = b_ih[256 + gr];
        biasNH[i] = b_hh[256 + gr];
        wout_r[i] = W_out[gr];
        h_old[i]  = 0.0f;
    }
    const float bout = b_out[0];

    {   // zero h buffer 0
        unsigned* hp = (unsigned*)&h_s[0][0][0];
        for (int i = tid; i < H_BUF / 2; i += 512) hp[i] = 0u;
    }

    // ---- x pipeline: 2 slots, loads issued 2 steps ahead ----
    const float* xb = x + (size_t)(b0 + bcol) * TSEQ * FDIM;
    float4 sA0, sA1, sA2, sA3, sB0, sB1, sB2, sB3;
    sA0 = *(const float4*)(xb + g4 * 8);
    sA1 = *(const float4*)(xb + g4 * 8 + 4);
    sA2 = *(const float4*)(xb + 32 + g4 * 8);
    sA3 = *(const float4*)(xb + 32 + g4 * 8 + 4);
    {
        const float* xp1 = xb + FDIM;
        sB0 = *(const float4*)(xp1 + g4 * 8);
        sB1 = *(const float4*)(xp1 + g4 * 8 + 4);
        sB2 = *(const float4*)(xp1 + 32 + g4 * 8);
        sB3 = *(const float4*)(xp1 + 32 + g4 * 8 + 4);
    }
    f16x8 xf0 = pack_f16(sA0, sA1);   // x(t) fragment kt=0
    f16x8 xf1 = pack_f16(sA2, sA3);   // x(t) fragment kt=1

    __syncthreads();   // prologue barrier

    const bool outw = (wid == 0) && (lane < 16);
    float* outp = out + (size_t)(b0 + lane) * TSEQ;
    float o0 = 0.f, o1 = 0.f, o2 = 0.f, o3 = 0.f;
    int rb = 0, wb = 1;

    for (int t = 0; t < TSEQ; t += 4) {
        #pragma unroll
        for (int u = 0; u < 4; ++u) {
            const int s = t + u;

            // ---- out path: out[s-1] from psum(s-1) (buffer rb) ----
            if (outw && s > 0) {
                f32x4 q0 = *(const f32x4*)&ps_s[rb][lane][0];
                f32x4 q1 = *(const f32x4*)&ps_s[rb][lane][4];
                float sm = (q0[0] + q0[1]) + (q0[2] + q0[3])
                         + (q1[0] + q1[1]) + (q1[2] + q1[3]);
                float val = fast_tanh(sm + bout);
                if (u == 0) {
                    o3 = val;
                    *(float4*)(outp + (t - 4)) = make_float4(o0, o1, o2, o3);
                } else if (u == 1) o0 = val;
                else if (u == 2) o1 = val;
                else o2 = val;
            }

            // ---- issue x(s+2) load into the free slot (clamped) ----
            {
                const int tl = (s + 2 < TSEQ) ? (s + 2) : (TSEQ - 1);
                const float* xp = xb + (size_t)tl * FDIM;
                if ((u & 1) == 0) {
                    sA0 = *(const float4*)(xp + g4 * 8);
                    sA1 = *(const float4*)(xp + g4 * 8 + 4);
                    sA2 = *(const float4*)(xp + 32 + g4 * 8);
                    sA3 = *(const float4*)(xp + 32 + g4 * 8 + 4);
                } else {
                    sB0 = *(const float4*)(xp + g4 * 8);
                    sB1 = *(const float4*)(xp + g4 * 8 + 4);
                    sB2 = *(const float4*)(xp + 32 + g4 * 8);
                    sB3 = *(const float4*)(xp + 32 + g4 * 8 + 4);
                }
            }

            // ---- h fragments (LDS, issued early) ----
            f16x8 bh0 = *(const f16x8*)&h_s[rb][bcol][0 * 32 + g4 * 8];
            f16x8 bh1 = *(const f16x8*)&h_s[rb][bcol][1 * 32 + g4 * 8];
            f16x8 bh2 = *(const f16x8*)&h_s[rb][bcol][2 * 32 + g4 * 8];
            f16x8 bh3 = *(const f16x8*)&h_s[rb][bcol][3 * 32 + g4 * 8];

            // ---- MFMA: 18 total; split a0/a1 into x/h partials for ILP ----
            f32x4 a0x = biasR, a1x = biasZ, a2 = biasNI, a3 = biasNH;
            f32x4 a0h = {0.f, 0.f, 0.f, 0.f}, a1h = {0.f, 0.f, 0.f, 0.f};

            // x-part (register fragments, no LDS dependency)
            a0x = mfma16f(WihF[0][0], xf0, a0x);
            a0x = mfma16f(WihF[0][1], xf1, a0x);
            a1x = mfma16f(WihF[1][0], xf0, a1x);
            a1x = mfma16f(WihF[1][1], xf1, a1x);
            a2  = mfma16f(WihF[2][0], xf0, a2);
            a2  = mfma16f(WihF[2][1], xf1, a2);

            // h-part
            a0h = mfma16f(WhhF[0][0], bh0, a0h);
            a1h = mfma16f(WhhF[1][0], bh0, a1h);
            a3  = mfma16f(WhhF[2][0], bh0, a3);
            a0h = mfma16f(WhhF[0][1], bh1, a0h);
            a1h = mfma16f(WhhF[1][1], bh1, a1h);
            a3  = mfma16f(WhhF[2][1], bh1, a3);
            a0h = mfma16f(WhhF[0][2], bh2, a0h);
            a1h = mfma16f(WhhF[1][2], bh2, a1h);
            a3  = mfma16f(WhhF[2][2], bh2, a3);
            a0h = mfma16f(WhhF[0][3], bh3, a0h);
            a1h = mfma16f(WhhF[1][3], bh3, a1h);
            a3  = mfma16f(WhhF[2][3], bh3, a3);

            const f32x4 a0 = a0x + a0h;
            const f32x4 a1 = a1x + a1h;

            // ---- gates (in-register) ----
            float psum = 0.0f;
            _Float16 h16[4];
            #pragma unroll
            for (int i = 0; i < 4; ++i) {
                float r  = fast_sig(a0[i]);
                float z  = fast_sig(a1[i]);
                float n  = fast_tanh(a2[i] + r * a3[i]);
                float hn = n + z * (h_old[i] - n);
                h_old[i] = hn;
                h16[i]   = (_Float16)hn;   // RNE
                psum = fmaf(wout_r[i], hn, psum);
            }
            psum += __shfl_xor(psum, 16);
            psum += __shfl_xor(psum, 32);

            // ---- writes to wb ----
            {
                union { _Float16 h[4]; uint2 u; } hu;
                hu.h[0] = h16[0]; hu.h[1] = h16[1];
                hu.h[2] = h16[2]; hu.h[3] = h16[3];
                *(uint2*)&h_s[wb][bcol][wid * 16 + g4 * 4] = hu.u;
            }
            if (lane < 16) ps_s[wb][lane][wid] = psum;

            // ---- convert x(s+1) fragments from the other slot ----
            if ((u & 1) == 0) {
                xf0 = pack_f16(sB0, sB1);
                xf1 = pack_f16(sB2, sB3);
            } else {
                xf0 = pack_f16(sA0, sA1);
                xf1 = pack_f16(sA2, sA3);
            }

            wg_barrier();
            rb = wb; wb = (wb == 2) ? 0 : wb + 1;
        }
    }

    // tail: out[511] from psum(511), in buffer (512 % 3) == 2
    if (outw) {
        f32x4 q0 = *(const f32x4*)&ps_s[2][lane][0];
        f32x4 q1 = *(const f32x4*)&ps_s[2][lane][4];
        float sm = (q0[0] + q0[1]) + (q0[2] + q0[3])
                 + (q1[0] + q1[1]) + (q1[2] + q1[3]);
        o3 = fast_tanh(sm + bout);
        *(float4*)(outp + (TSEQ - 4)) = make_float4(o0, o1, o2, o3);
    }
}

extern "C" void kernel_launch(void* const* d_in, const int* in_sizes, int n_in,
                              void* d_out, int out_size, void* d_ws, size_t ws_size,
                              hipStream_t stream) {
    const float* x     = (const float*)d_in[0];
    const float* W_ih  = (const float*)d_in[1];
    const float* W_hh  = (const float*)d_in[2];
    const float* b_ih  = (const float*)d_in[3];
    const float* b_hh  = (const float*)d_in[4];
    const float* W_out = (const float*)d_in[5];
    const float* b_out = (const float*)d_in[6];
    float* out = (float*)d_out;

    gru_f16<<<32, 512, 0, stream>>>(x, W_ih, W_hh, b_ih, b_hh, W_out, b_out, out);
}